// Round 1
// baseline (669.271 us; speedup 1.0000x reference)
//
#include <hip/hip_runtime.h>
#include <hip/hip_bf16.h>
#include <stdint.h>

#define NTOK 98
#define DIM 128
#define HEADS 4
#define HD 32
#define BWIN 2048
#define NW 64
#define SCALE 0.17677669529663687f

typedef __bf16 bf16_t;
typedef bf16_t bf16x8 __attribute__((ext_vector_type(8)));
typedef float f32x4 __attribute__((ext_vector_type(4)));
typedef unsigned short u16;
typedef unsigned int u32;
typedef unsigned long long u64;

__device__ __forceinline__ u16 f2bf(float f) {
    union { float f; u32 u; } v; v.f = f;
    u32 r = v.u + 0x7FFFu + ((v.u >> 16) & 1u);
    return (u16)(r >> 16);
}
__device__ __forceinline__ float bf2f(u16 b) {
    union { u32 u; float f; } v; v.u = ((u32)b) << 16;
    return v.f;
}

// ---------------- K0: prep (bias gather + weight bf16 conversion) -------------
__global__ void k0_prep(const float* __restrict__ qkv_w, const float* __restrict__ proj_w,
                        const float* __restrict__ bias_table, const int* __restrict__ rel_idx,
                        u16* __restrict__ qkvw_bf, u16* __restrict__ pw_bf,
                        float* __restrict__ bias_pre)
{
    int t = blockIdx.x * 256 + threadIdx.x;
    if (t < 49152) {
        qkvw_bf[t] = f2bf(qkv_w[t]);
    } else if (t < 65536) {
        int r = t - 49152;
        pw_bf[r] = f2bf(proj_w[r]);
    } else if (t < 103952) {
        int r = t - 65536;
        int hh = r / 9604;
        int ij = r - hh * 9604;
        bias_pre[hh * 9604 + ij] = bias_table[rel_idx[ij] * HEADS + hh];
    }
}

// ---------------- K1: fused per-(window, head) attention ----------------------
// LDS map (u16 units):
//   Xbf  [112][136] @ 0      (phase A/B)  -- reused as pL [112][120] (phase C/D)
//   Wb   [32][136]  @ 15232
//   qS   [112][40]  @ 19584
//   kS   [112][40]  @ 24064
//   vT   [32][120]  @ 28544   (vT[d][token])
// total 32384 u16 = 64768 B
__global__ __launch_bounds__(256) void k1_attn(
    const float* __restrict__ x, const float* __restrict__ mask,
    const u16* __restrict__ qkvw_bf, const float* __restrict__ qkv_b,
    const float* __restrict__ bias_pre, u16* __restrict__ attnout)
{
    __shared__ __align__(16) u16 smem[32384];
    u16* Xbf = smem;
    u16* Wb  = smem + 15232;
    u16* qS  = smem + 19584;
    u16* kS  = smem + 24064;
    u16* vT  = smem + 28544;

    const int b    = blockIdx.x;
    const int h    = blockIdx.y;
    const int tid  = threadIdx.x;
    const int wave = tid >> 6;
    const int lane = tid & 63;
    const int l16  = lane & 15;
    const int quad = lane >> 4;

    // ---- Phase A: stage x[b] -> bf16 LDS, zero pad rows 98..111 ----
    const float* xb = x + (size_t)b * (NTOK * DIM);
    for (int idx = tid; idx < (NTOK * DIM / 4); idx += 256) {
        int row = idx >> 5;           // 32 float4 per row
        int c4  = idx & 31;
        const float4 v = reinterpret_cast<const float4*>(xb)[idx];
        u64 pack = (u64)f2bf(v.x) | ((u64)f2bf(v.y) << 16) |
                   ((u64)f2bf(v.z) << 32) | ((u64)f2bf(v.w) << 48);
        *reinterpret_cast<u64*>(&Xbf[row * 136 + c4 * 4]) = pack;
    }
    for (int idx = tid; idx < 952; idx += 256) {   // 14 rows * 136 = 1904 u16
        reinterpret_cast<u32*>(Xbf + 98 * 136)[idx] = 0u;
    }
    __syncthreads();

    // ---- Phase B: q/k/v = X @ Wp^T + b (per part) ----
    for (int part = 0; part < 3; ++part) {
        const u16* wsrc = qkvw_bf + (size_t)(part * DIM + h * HD) * DIM;
        for (int idx = tid; idx < 512; idx += 256) {   // 32 rows * 16 chunks of 8
            int row = idx >> 4, c8 = idx & 15;
            int4 vv = *reinterpret_cast<const int4*>(wsrc + row * DIM + c8 * 8);
            *reinterpret_cast<int4*>(&Wb[row * 136 + c8 * 8]) = vv;
        }
        __syncthreads();

        for (int t = wave; t < 14; t += 4) {
            int mt = t >> 1;
            int nt = t & 1;
            f32x4 acc = {0.f, 0.f, 0.f, 0.f};
#pragma unroll
            for (int ks = 0; ks < 4; ++ks) {
                bf16x8 af = *reinterpret_cast<const bf16x8*>(
                    &Xbf[(mt * 16 + l16) * 136 + quad * 8 + ks * 32]);
                bf16x8 bw = *reinterpret_cast<const bf16x8*>(
                    &Wb[(nt * 16 + l16) * 136 + quad * 8 + ks * 32]);
                acc = __builtin_amdgcn_mfma_f32_16x16x32_bf16(af, bw, acc, 0, 0, 0);
            }
            int d = nt * 16 + l16;                       // 0..31 within head
            float cbias = qkv_b[part * DIM + h * HD + d];
            if (part == 2) {
                // v -> vT[d][token], 4 consecutive tokens packed
                u64 pack = 0;
#pragma unroll
                for (int reg = 0; reg < 4; ++reg) {
                    pack |= ((u64)f2bf(acc[reg] + cbias)) << (16 * reg);
                }
                *reinterpret_cast<u64*>(&vT[d * 120 + mt * 16 + quad * 4]) = pack;
            } else {
                u16* dst = (part == 0) ? qS : kS;
                float mul = (part == 0) ? SCALE : 1.0f;
#pragma unroll
                for (int reg = 0; reg < 4; ++reg) {
                    int tok = mt * 16 + quad * 4 + reg;
                    dst[tok * 40 + d] = f2bf((acc[reg] + cbias) * mul);
                }
            }
        }
        __syncthreads();
    }

    // ---- Phase C: S = q k^T + bias + mask, softmax -> pL (bf16) ----
    const float* maskp = mask + (size_t)(b & (NW - 1)) * (NTOK * NTOK);
    const float* biasp = bias_pre + (size_t)h * (NTOK * NTOK);
    u16* pL = Xbf;  // [112][120]

    for (int mt = wave; mt < 7; mt += 4) {
        f32x4 sacc[7];
#pragma unroll
        for (int nj = 0; nj < 7; ++nj) {
            bf16x8 af = *reinterpret_cast<const bf16x8*>(&qS[(mt * 16 + l16) * 40 + quad * 8]);
            bf16x8 bk = *reinterpret_cast<const bf16x8*>(&kS[(nj * 16 + l16) * 40 + quad * 8]);
            f32x4 z = {0.f, 0.f, 0.f, 0.f};
            sacc[nj] = __builtin_amdgcn_mfma_f32_16x16x32_bf16(af, bk, z, 0, 0, 0);
        }
#pragma unroll
        for (int reg = 0; reg < 4; ++reg) {
            int i = mt * 16 + quad * 4 + reg;
            bool irow = (i < NTOK);
            float s[7];
#pragma unroll
            for (int nj = 0; nj < 7; ++nj) {
                int j = nj * 16 + l16;
                float val = -1e30f;
                if (irow && j < NTOK) {
                    val = sacc[nj][reg] + biasp[i * NTOK + j] + maskp[i * NTOK + j];
                }
                s[nj] = val;
            }
            float mx = s[0];
#pragma unroll
            for (int nj = 1; nj < 7; ++nj) mx = fmaxf(mx, s[nj]);
#pragma unroll
            for (int off = 1; off < 16; off <<= 1) mx = fmaxf(mx, __shfl_xor(mx, off));
            float p[7];
            float lsum = 0.f;
#pragma unroll
            for (int nj = 0; nj < 7; ++nj) {
                float pv = (s[nj] > -1e29f) ? __expf(s[nj] - mx) : 0.f;
                p[nj] = pv;
                lsum += pv;
            }
#pragma unroll
            for (int off = 1; off < 16; off <<= 1) lsum += __shfl_xor(lsum, off);
            float rinv = 1.f / ((lsum > 0.f) ? lsum : 1.f);
#pragma unroll
            for (int nj = 0; nj < 7; ++nj) {
                int j = nj * 16 + l16;
                if (j < NTOK) pL[i * 120 + j] = f2bf(p[nj] * rinv);
            }
        }
    }
    // no barrier needed: each wave reads back only the pL rows it wrote

    // ---- Phase D: O = P V (3 full K-steps over tokens 0..95 + scalar tail 96,97) ----
    for (int mt = wave; mt < 7; mt += 4) {
#pragma unroll
        for (int nt = 0; nt < 2; ++nt) {
            f32x4 acc = {0.f, 0.f, 0.f, 0.f};
#pragma unroll
            for (int ks = 0; ks < 3; ++ks) {
                bf16x8 af = *reinterpret_cast<const bf16x8*>(
                    &pL[(mt * 16 + l16) * 120 + quad * 8 + ks * 32]);
                bf16x8 bv = *reinterpret_cast<const bf16x8*>(
                    &vT[(nt * 16 + l16) * 120 + quad * 8 + ks * 32]);
                acc = __builtin_amdgcn_mfma_f32_16x16x32_bf16(af, bv, acc, 0, 0, 0);
            }
            int d = nt * 16 + l16;
            float v96 = bf2f(vT[d * 120 + 96]);
            float v97 = bf2f(vT[d * 120 + 97]);
#pragma unroll
            for (int reg = 0; reg < 4; ++reg) {
                int i = mt * 16 + quad * 4 + reg;
                float p96 = bf2f(pL[i * 120 + 96]);
                float p97 = bf2f(pL[i * 120 + 97]);
                float val = acc[reg] + p96 * v96 + p97 * v97;
                if (i < NTOK) {
                    attnout[((size_t)b * NTOK + i) * DIM + h * HD + d] = f2bf(val);
                }
            }
        }
    }
}

// ---------------- K2: proj GEMM  out = A @ proj_w^T + proj_b ------------------
__global__ __launch_bounds__(256) void k2_proj(
    const u16* __restrict__ attnout, const u16* __restrict__ pw_bf,
    const float* __restrict__ proj_b, float* __restrict__ out)
{
    __shared__ __align__(16) u16 smem2[26112];  // As [64][136] + Ws [128][136]
    u16* As = smem2;
    u16* Ws = smem2 + 8704;

    const int tid  = threadIdx.x;
    const int wave = tid >> 6;
    const int lane = tid & 63;
    const int l16  = lane & 15;
    const int quad = lane >> 4;
    const size_t r0 = (size_t)blockIdx.x * 64;

    for (int idx = tid; idx < 1024; idx += 256) {   // 64 rows * 16 chunks
        int row = idx >> 4, c8 = idx & 15;
        int4 v = *reinterpret_cast<const int4*>(attnout + (r0 + row) * DIM + c8 * 8);
        *reinterpret_cast<int4*>(&As[row * 136 + c8 * 8]) = v;
    }
    for (int idx = tid; idx < 2048; idx += 256) {   // 128 rows * 16 chunks
        int row = idx >> 4, c8 = idx & 15;
        int4 v = *reinterpret_cast<const int4*>(pw_bf + row * DIM + c8 * 8);
        *reinterpret_cast<int4*>(&Ws[row * 136 + c8 * 8]) = v;
    }
    __syncthreads();

    for (int t = wave; t < 32; t += 4) {
        int mt = t >> 3, nt = t & 7;
        f32x4 acc = {0.f, 0.f, 0.f, 0.f};
#pragma unroll
        for (int ks = 0; ks < 4; ++ks) {
            bf16x8 af = *reinterpret_cast<const bf16x8*>(
                &As[(mt * 16 + l16) * 136 + quad * 8 + ks * 32]);
            bf16x8 bw = *reinterpret_cast<const bf16x8*>(
                &Ws[(nt * 16 + l16) * 136 + quad * 8 + ks * 32]);
            acc = __builtin_amdgcn_mfma_f32_16x16x32_bf16(af, bw, acc, 0, 0, 0);
        }
        int col = nt * 16 + l16;
        float pb = proj_b[col];
#pragma unroll
        for (int reg = 0; reg < 4; ++reg) {
            int row = mt * 16 + quad * 4 + reg;
            out[(r0 + row) * DIM + col] = acc[reg] + pb;
        }
    }
}

// ---------------- launch ------------------------------------------------------
extern "C" void kernel_launch(void* const* d_in, const int* in_sizes, int n_in,
                              void* d_out, int out_size, void* d_ws, size_t ws_size,
                              hipStream_t stream)
{
    const float* x       = (const float*)d_in[0];
    const float* mask    = (const float*)d_in[1];
    const float* qkv_w   = (const float*)d_in[2];
    const float* qkv_b   = (const float*)d_in[3];
    const float* proj_w  = (const float*)d_in[4];
    const float* proj_b  = (const float*)d_in[5];
    const float* bias_tb = (const float*)d_in[6];
    const int*   rel_idx = (const int*)d_in[7];
    float* out = (float*)d_out;

    char* ws = (char*)d_ws;
    u16*   qkvw_bf = (u16*)(ws + 0);        //  98304 B
    u16*   pw_bf   = (u16*)(ws + 98304);    //  32768 B
    float* biaspre = (float*)(ws + 131072); // 153664 B
    u16*   attnout = (u16*)(ws + 294912);   // 51380224 B

    k0_prep<<<407, 256, 0, stream>>>(qkv_w, proj_w, bias_tb, rel_idx,
                                     qkvw_bf, pw_bf, biaspre);
    dim3 g1(BWIN, HEADS);
    k1_attn<<<g1, 256, 0, stream>>>(x, mask, qkvw_bf, qkv_b, biaspre, attnout);
    k2_proj<<<(BWIN * NTOK) / 64, 256, 0, stream>>>(attnout, pw_bf, proj_b, out);
}

// Round 2
// 613.916 us; speedup vs baseline: 1.0902x; 1.0902x over previous
//
#include <hip/hip_runtime.h>
#include <hip/hip_bf16.h>
#include <stdint.h>

#define NTOK 98
#define DIM 128
#define HEADS 4
#define HD 32
#define BWIN 2048
#define NW 64
#define SCALE 0.17677669529663687f

// LDS strides (u16 units; all multiples of 8 => 16B-aligned rows for ds_read_b128)
#define XS 136   // Xbf [98][136]
#define QS 40    // qS/kS [112][40]
#define VS 120   // vT [32][120]
#define PS 104   // pL [112][104] (overlays Xbf region)

#define XBF0 0
#define QS0  13328
#define KS0  17808
#define VT0  22288
#define LDS_TOT 26128   // u16 = 52256 B -> 3 blocks/CU

typedef __bf16 bf16_t;
typedef bf16_t bf16x8 __attribute__((ext_vector_type(8)));
typedef float f32x4 __attribute__((ext_vector_type(4)));
typedef unsigned short u16;
typedef unsigned int u32;
typedef unsigned long long u64;

__device__ __forceinline__ u16 f2bf(float f) {
    union { float f; u32 u; } v; v.f = f;
    u32 r = v.u + 0x7FFFu + ((v.u >> 16) & 1u);
    return (u16)(r >> 16);
}
__device__ __forceinline__ float bf2f(u16 b) {
    union { u32 u; float f; } v; v.u = ((u32)b) << 16;
    return v.f;
}

// ---------------- K0: prep (bias gather + weight bf16 conversion) -------------
__global__ void k0_prep(const float* __restrict__ qkv_w, const float* __restrict__ proj_w,
                        const float* __restrict__ bias_table, const int* __restrict__ rel_idx,
                        u16* __restrict__ qkvw_bf, u16* __restrict__ pw_bf,
                        float* __restrict__ bias_pre)
{
    int t = blockIdx.x * 256 + threadIdx.x;
    if (t < 49152) {
        qkvw_bf[t] = f2bf(qkv_w[t]);
    } else if (t < 65536) {
        int r = t - 49152;
        pw_bf[r] = f2bf(proj_w[r]);
    } else if (t < 103952) {
        int r = t - 65536;
        int hh = r / 9604;
        int ij = r - hh * 9604;
        bias_pre[hh * 9604 + ij] = bias_table[rel_idx[ij] * HEADS + hh];
    }
}

// ---------------- K1: fused per-(window, head) attention ----------------------
// LDS (u16): Xbf [98][136] @0 (reused as pL [112][104] in phases C/D)
//            qS  [112][40] @13328, kS [112][40] @17808, vT [32][120] @22288
// total 52256 B -> 3 blocks/CU, 2 barriers per block.
__global__ __launch_bounds__(256, 3) void k1_attn(
    const float* __restrict__ x, const float* __restrict__ mask,
    const u16* __restrict__ qkvw_bf, const float* __restrict__ qkv_b,
    const float* __restrict__ bias_pre, u16* __restrict__ attnout)
{
    __shared__ __align__(16) u16 smem[LDS_TOT];
    u16* Xbf = smem + XBF0;
    u16* qS  = smem + QS0;
    u16* kS  = smem + KS0;
    u16* vT  = smem + VT0;

    const int b    = blockIdx.x;
    const int h    = blockIdx.y;
    const int tid  = threadIdx.x;
    const int wave = tid >> 6;
    const int lane = tid & 63;
    const int l16  = lane & 15;
    const int quad = lane >> 4;

    // ---- Phase A: stage x[b] -> bf16 LDS (98 rows only, no pad) ----
    const float* xb = x + (size_t)b * (NTOK * DIM);
    for (int idx = tid; idx < (NTOK * DIM / 4); idx += 256) {
        int row = idx >> 5;
        int c4  = idx & 31;
        const float4 v = reinterpret_cast<const float4*>(xb)[idx];
        u64 pack = (u64)f2bf(v.x) | ((u64)f2bf(v.y) << 16) |
                   ((u64)f2bf(v.z) << 32) | ((u64)f2bf(v.w) << 48);
        *reinterpret_cast<u64*>(&Xbf[row * XS + c4 * 4]) = pack;
    }
    __syncthreads();

    // ---- Phase B: q/k/v = X @ Wp^T + b ----
    // 21 (part,mt) units round-robin over waves; B-frags direct from global,
    // register-cached while part is unchanged (wave-uniform branch).
    {
        bf16x8 bfr[2][4];
        int lastPart = -1;
        for (int u = wave; u < 21; u += 4) {
            int part = u / 7;
            int mt   = u % 7;
            if (part != lastPart) {
                lastPart = part;
                const u16* wp = qkvw_bf + ((size_t)part * DIM + h * HD) * DIM;
#pragma unroll
                for (int nt2 = 0; nt2 < 2; ++nt2)
#pragma unroll
                    for (int ks = 0; ks < 4; ++ks)
                        bfr[nt2][ks] = *reinterpret_cast<const bf16x8*>(
                            wp + (nt2 * 16 + l16) * DIM + quad * 8 + ks * 32);
            }
            int arow = mt * 16 + l16;
            if (arow > 97) arow = 97;   // pad rows duplicate row 97 (outputs discarded)
            bf16x8 af[4];
#pragma unroll
            for (int ks = 0; ks < 4; ++ks)
                af[ks] = *reinterpret_cast<const bf16x8*>(&Xbf[arow * XS + quad * 8 + ks * 32]);
            f32x4 acc0 = {0.f, 0.f, 0.f, 0.f};
            f32x4 acc1 = {0.f, 0.f, 0.f, 0.f};
#pragma unroll
            for (int ks = 0; ks < 4; ++ks) {
                acc0 = __builtin_amdgcn_mfma_f32_16x16x32_bf16(af[ks], bfr[0][ks], acc0, 0, 0, 0);
                acc1 = __builtin_amdgcn_mfma_f32_16x16x32_bf16(af[ks], bfr[1][ks], acc1, 0, 0, 0);
            }
            int tokb = mt * 16 + quad * 4;
#pragma unroll
            for (int nt2 = 0; nt2 < 2; ++nt2) {
                const f32x4& acc = nt2 ? acc1 : acc0;
                int d = nt2 * 16 + l16;
                float cbias = qkv_b[part * DIM + h * HD + d];
                if (part == 2) {
                    u64 pack = 0;
#pragma unroll
                    for (int reg = 0; reg < 4; ++reg)
                        pack |= ((u64)f2bf(acc[reg] + cbias)) << (16 * reg);
                    *reinterpret_cast<u64*>(&vT[d * VS + tokb]) = pack;
                } else {
                    u16* dst = (part == 0) ? qS : kS;
                    float mul = (part == 0) ? SCALE : 1.0f;
#pragma unroll
                    for (int reg = 0; reg < 4; ++reg)
                        dst[(tokb + reg) * QS + d] = f2bf((acc[reg] + cbias) * mul);
                }
            }
        }
    }
    __syncthreads();

    // ---- Phase C: S = q k^T + bias + mask, softmax -> pL (bf16) ----
    const float* maskp = mask + (size_t)(b & (NW - 1)) * (NTOK * NTOK);
    const float* biasp = bias_pre + (size_t)h * (NTOK * NTOK);
    u16* pL = Xbf;  // overlay: Xbf dead after phase B

    for (int mt = wave; mt < 7; mt += 4) {
        int arow = mt * 16 + l16;      // <= 111, within 112-row qS
        bf16x8 af = *reinterpret_cast<const bf16x8*>(&qS[arow * QS + quad * 8]);
        f32x4 sacc[7];
#pragma unroll
        for (int nj = 0; nj < 7; ++nj) {
            bf16x8 bk = *reinterpret_cast<const bf16x8*>(&kS[(nj * 16 + l16) * QS + quad * 8]);
            f32x4 z = {0.f, 0.f, 0.f, 0.f};
            sacc[nj] = __builtin_amdgcn_mfma_f32_16x16x32_bf16(af, bk, z, 0, 0, 0);
        }
#pragma unroll
        for (int reg = 0; reg < 4; ++reg) {
            int i = mt * 16 + quad * 4 + reg;
            bool irow = (i < NTOK);
            float s[7];
#pragma unroll
            for (int nj = 0; nj < 7; ++nj) {
                int j = nj * 16 + l16;
                float val = -1e30f;
                if (irow && j < NTOK)
                    val = sacc[nj][reg] + biasp[i * NTOK + j] + maskp[i * NTOK + j];
                s[nj] = val;
            }
            float mx = s[0];
#pragma unroll
            for (int nj = 1; nj < 7; ++nj) mx = fmaxf(mx, s[nj]);
#pragma unroll
            for (int off = 1; off < 16; off <<= 1) mx = fmaxf(mx, __shfl_xor(mx, off));
            float p[7];
            float lsum = 0.f;
#pragma unroll
            for (int nj = 0; nj < 7; ++nj) {
                float pv = (s[nj] > -1e29f) ? __expf(s[nj] - mx) : 0.f;
                p[nj] = pv;
                lsum += pv;
            }
#pragma unroll
            for (int off = 1; off < 16; off <<= 1) lsum += __shfl_xor(lsum, off);
            float rinv = 1.f / ((lsum > 0.f) ? lsum : 1.f);
#pragma unroll
            for (int nj = 0; nj < 7; ++nj) {
                int j = nj * 16 + l16;
                if (irow && j < NTOK) pL[i * PS + j] = f2bf(p[nj] * rinv);
            }
        }
    }
    // no barrier: each wave reads back only the pL rows it wrote (vT covered by B->C barrier)

    // ---- Phase D: O = P V (3 MFMA K-steps tokens 0..95 + scalar tail 96,97) ----
    for (int mt = wave; mt < 7; mt += 4) {
        bf16x8 af[3];
#pragma unroll
        for (int ks = 0; ks < 3; ++ks)
            af[ks] = *reinterpret_cast<const bf16x8*>(
                &pL[(mt * 16 + l16) * PS + quad * 8 + ks * 32]);
#pragma unroll
        for (int nt = 0; nt < 2; ++nt) {
            f32x4 acc = {0.f, 0.f, 0.f, 0.f};
#pragma unroll
            for (int ks = 0; ks < 3; ++ks) {
                bf16x8 bv = *reinterpret_cast<const bf16x8*>(
                    &vT[(nt * 16 + l16) * VS + quad * 8 + ks * 32]);
                acc = __builtin_amdgcn_mfma_f32_16x16x32_bf16(af[ks], bv, acc, 0, 0, 0);
            }
            int d = nt * 16 + l16;
            float v96 = bf2f(vT[d * VS + 96]);
            float v97 = bf2f(vT[d * VS + 97]);
#pragma unroll
            for (int reg = 0; reg < 4; ++reg) {
                int i = mt * 16 + quad * 4 + reg;
                if (i < NTOK) {
                    float p96 = bf2f(pL[i * PS + 96]);
                    float p97 = bf2f(pL[i * PS + 97]);
                    float val = acc[reg] + p96 * v96 + p97 * v97;
                    attnout[((size_t)b * NTOK + i) * DIM + h * HD + d] = f2bf(val);
                }
            }
        }
    }
}

// ---------------- K2: proj GEMM, no LDS (fragments direct from global) --------
__global__ __launch_bounds__(256) void k2_proj(
    const u16* __restrict__ attnout, const u16* __restrict__ pw_bf,
    const float* __restrict__ proj_b, float* __restrict__ out)
{
    const int tid  = threadIdx.x;
    const int wave = tid >> 6;
    const int lane = tid & 63;
    const int l16  = lane & 15;
    const int quad = lane >> 4;
    const size_t r0 = (size_t)blockIdx.x * 64 + wave * 16;   // 16-row strip per wave

    bf16x8 af[4];
#pragma unroll
    for (int ks = 0; ks < 4; ++ks)
        af[ks] = *reinterpret_cast<const bf16x8*>(
            attnout + (r0 + l16) * DIM + quad * 8 + ks * 32);

#pragma unroll
    for (int nt = 0; nt < 8; ++nt) {
        f32x4 acc = {0.f, 0.f, 0.f, 0.f};
#pragma unroll
        for (int ks = 0; ks < 4; ++ks) {
            bf16x8 bw = *reinterpret_cast<const bf16x8*>(
                pw_bf + (nt * 16 + l16) * DIM + quad * 8 + ks * 32);
            acc = __builtin_amdgcn_mfma_f32_16x16x32_bf16(af[ks], bw, acc, 0, 0, 0);
        }
        int col = nt * 16 + l16;
        float pb = proj_b[col];
#pragma unroll
        for (int reg = 0; reg < 4; ++reg) {
            size_t row = r0 + quad * 4 + reg;
            out[row * DIM + col] = acc[reg] + pb;
        }
    }
}

// ---------------- launch ------------------------------------------------------
extern "C" void kernel_launch(void* const* d_in, const int* in_sizes, int n_in,
                              void* d_out, int out_size, void* d_ws, size_t ws_size,
                              hipStream_t stream)
{
    const float* x       = (const float*)d_in[0];
    const float* mask    = (const float*)d_in[1];
    const float* qkv_w   = (const float*)d_in[2];
    const float* qkv_b   = (const float*)d_in[3];
    const float* proj_w  = (const float*)d_in[4];
    const float* proj_b  = (const float*)d_in[5];
    const float* bias_tb = (const float*)d_in[6];
    const int*   rel_idx = (const int*)d_in[7];
    float* out = (float*)d_out;

    char* ws = (char*)d_ws;
    u16*   qkvw_bf = (u16*)(ws + 0);        //  98304 B
    u16*   pw_bf   = (u16*)(ws + 98304);    //  32768 B
    float* biaspre = (float*)(ws + 131072); // 153664 B
    u16*   attnout = (u16*)(ws + 294912);   // 51380224 B

    k0_prep<<<407, 256, 0, stream>>>(qkv_w, proj_w, bias_tb, rel_idx,
                                     qkvw_bf, pw_bf, biaspre);
    dim3 g1(BWIN, HEADS);
    k1_attn<<<g1, 256, 0, stream>>>(x, mask, qkvw_bf, qkv_b, biaspre, attnout);
    k2_proj<<<(BWIN * NTOK) / 64, 256, 0, stream>>>(attnout, pw_bf, proj_b, out);
}

// Round 3
// 551.479 us; speedup vs baseline: 1.2136x; 1.1132x over previous
//
#include <hip/hip_runtime.h>
#include <hip/hip_bf16.h>
#include <stdint.h>

#define NTOK 98
#define DIM 128
#define HEADS 4
#define HD 32
#define BWIN 2048
#define NW 64
#define SCALE 0.17677669529663687f

typedef __bf16 bf16_t;
typedef bf16_t bf16x8 __attribute__((ext_vector_type(8)));
typedef float f32x4 __attribute__((ext_vector_type(4)));
typedef unsigned short u16;
typedef unsigned int u32;
typedef unsigned long long u64;

__device__ __forceinline__ u16 f2bf(float f) {
    union { float f; u32 u; } v; v.f = f;
    u32 r = v.u + 0x7FFFu + ((v.u >> 16) & 1u);
    return (u16)(r >> 16);
}
__device__ __forceinline__ float bf2f(u16 b) {
    union { u32 u; float f; } v; v.u = ((u32)b) << 16;
    return v.f;
}

// ---------------- K0: prep ----------------------------------------------------
// [0,49152)        qkv_w -> bf16
// [49152,65536)    proj_w -> bf16
// [65536,2524160)  mb[w][h][i*98+j] = bf16(mask[w][ij] + bias_table[rel_idx[ij]][h])
__global__ void k0_prep(const float* __restrict__ qkv_w, const float* __restrict__ proj_w,
                        const float* __restrict__ mask,
                        const float* __restrict__ bias_table, const int* __restrict__ rel_idx,
                        u16* __restrict__ qkvw_bf, u16* __restrict__ pw_bf,
                        u16* __restrict__ mb)
{
    int t = blockIdx.x * 256 + threadIdx.x;
    if (t < 49152) {
        qkvw_bf[t] = f2bf(qkv_w[t]);
    } else if (t < 65536) {
        int r = t - 49152;
        pw_bf[r] = f2bf(proj_w[r]);
    } else if (t < 2524160) {
        int r = t - 65536;                 // [0, 64*4*9604)
        int w   = r / (HEADS * 9604);
        int rem = r - w * (HEADS * 9604);
        int hh  = rem / 9604;
        int ij  = rem - hh * 9604;
        mb[r] = f2bf(mask[w * 9604 + ij] + bias_table[rel_idx[ij] * HEADS + hh]);
    }
}

// ---------------- K1: qkv GEMM per window ------------------------------------
// Writes (bf16):
//   qG[(b*4+h)][tok][d32]  (pre-scaled by SCALE)
//   kG[(b*4+h)][tok][d32]
//   vG[(b*4+h)][d32][tok(pad 104)]   (transposed -> B-frag layout for PV)
__global__ __launch_bounds__(256) void k1_qkv(
    const float* __restrict__ x, const u16* __restrict__ qkvw_bf,
    const float* __restrict__ qkv_b,
    u16* __restrict__ qG, u16* __restrict__ kG, u16* __restrict__ vG)
{
    __shared__ __align__(16) u16 Xbf[98 * 136];

    const int b    = blockIdx.x;
    const int tid  = threadIdx.x;
    const int wave = tid >> 6;
    const int lane = tid & 63;
    const int l16  = lane & 15;
    const int quad = lane >> 4;

    // stage x[b] -> bf16 LDS
    const float* xb = x + (size_t)b * (NTOK * DIM);
    for (int idx = tid; idx < (NTOK * DIM / 4); idx += 256) {
        int row = idx >> 5;
        int c4  = idx & 31;
        const float4 v = reinterpret_cast<const float4*>(xb)[idx];
        u64 pack = (u64)f2bf(v.x) | ((u64)f2bf(v.y) << 16) |
                   ((u64)f2bf(v.z) << 32) | ((u64)f2bf(v.w) << 48);
        *reinterpret_cast<u64*>(&Xbf[row * 136 + c4 * 4]) = pack;
    }
    __syncthreads();

    // 21 (part, mt) units round-robin over waves; full N=128 per unit
    for (int u = wave; u < 21; u += 4) {
        int part = u / 7;
        int mt   = u % 7;
        int arow = mt * 16 + l16;
        if (arow > 97) arow = 97;          // pad rows duplicate row 97 (discarded)
        bf16x8 af[4];
#pragma unroll
        for (int ks = 0; ks < 4; ++ks)
            af[ks] = *reinterpret_cast<const bf16x8*>(&Xbf[arow * 136 + quad * 8 + ks * 32]);
        const int tokb = mt * 16 + quad * 4;
        const u16* wp = qkvw_bf + (size_t)part * DIM * DIM;

#pragma unroll
        for (int np = 0; np < 4; ++np) {   // nt pairs: (2np, 2np+1)
            f32x4 acc0 = {0.f, 0.f, 0.f, 0.f};
            f32x4 acc1 = {0.f, 0.f, 0.f, 0.f};
#pragma unroll
            for (int ks = 0; ks < 4; ++ks) {
                bf16x8 b0 = *reinterpret_cast<const bf16x8*>(
                    wp + ((np * 2 + 0) * 16 + l16) * DIM + quad * 8 + ks * 32);
                bf16x8 b1 = *reinterpret_cast<const bf16x8*>(
                    wp + ((np * 2 + 1) * 16 + l16) * DIM + quad * 8 + ks * 32);
                acc0 = __builtin_amdgcn_mfma_f32_16x16x32_bf16(af[ks], b0, acc0, 0, 0, 0);
                acc1 = __builtin_amdgcn_mfma_f32_16x16x32_bf16(af[ks], b1, acc1, 0, 0, 0);
            }
#pragma unroll
            for (int half = 0; half < 2; ++half) {
                const f32x4& acc = half ? acc1 : acc0;
                int col = (np * 2 + half) * 16 + l16;     // 0..127
                int h   = col >> 5;
                int d   = col & 31;
                float cb = qkv_b[part * DIM + col];
                size_t bh = (size_t)b * HEADS + h;
                if (part == 0) {
#pragma unroll
                    for (int reg = 0; reg < 4; ++reg) {
                        int tok = tokb + reg;
                        if (tok < NTOK)
                            qG[(bh * NTOK + tok) * HD + d] = f2bf((acc[reg] + cb) * SCALE);
                    }
                } else if (part == 1) {
#pragma unroll
                    for (int reg = 0; reg < 4; ++reg) {
                        int tok = tokb + reg;
                        if (tok < NTOK)
                            kG[(bh * NTOK + tok) * HD + d] = f2bf(acc[reg] + cb);
                    }
                } else {
                    u16* vrow = vG + (bh * HD + d) * 104;
                    if (tokb + 3 <= 97) {
                        u64 pack = 0;
#pragma unroll
                        for (int reg = 0; reg < 4; ++reg)
                            pack |= ((u64)f2bf(acc[reg] + cb)) << (16 * reg);
                        *reinterpret_cast<u64*>(&vrow[tokb]) = pack;
                    } else if (tokb <= 97) {   // tokb == 96: tokens 96,97
                        u32 pack = (u32)f2bf(acc[0] + cb) | ((u32)f2bf(acc[1] + cb) << 16);
                        *reinterpret_cast<u32*>(&vrow[tokb]) = pack;
                    }
                }
            }
        }
    }
}

// ---------------- K2: attention (wave per head) + fused proj ------------------
// LDS: Obuf [98][136] u16 (13328) + Pscr [4][16*104] u16 (6656) = 39968 B
// Attention phase is barrier-free (all per-wave private); one barrier before proj.
__global__ __launch_bounds__(256, 4) void k2_attn(
    const u16* __restrict__ qG, const u16* __restrict__ kG, const u16* __restrict__ vG,
    const u16* __restrict__ mb, const u16* __restrict__ pw_bf,
    const float* __restrict__ proj_b, float* __restrict__ out)
{
    __shared__ __align__(16) u16 Obuf[98 * 136];
    __shared__ __align__(16) u16 Pscr[4][16 * 104];

    const int b    = blockIdx.x;
    const int tid  = threadIdx.x;
    const int wave = tid >> 6;
    const int lane = tid & 63;
    const int l16  = lane & 15;
    const int quad = lane >> 4;
    const int h    = wave;                    // wave <-> head

    const size_t bh = (size_t)b * HEADS + h;
    const u16* qb  = qG + bh * (NTOK * HD);
    const u16* kb  = kG + bh * (NTOK * HD);
    const u16* vb  = vG + bh * (HD * 104);
    const u16* mbp = mb + ((size_t)((b & (NW - 1)) * HEADS + h)) * 9604;
    u16* ps = &Pscr[wave][0];

    // K fragments held in registers for the whole mt loop (28 VGPRs)
    bf16x8 kf[7];
#pragma unroll
    for (int nj = 0; nj < 7; ++nj)
        kf[nj] = *reinterpret_cast<const bf16x8*>(kb + (nj * 16 + l16) * HD + quad * 8);

    for (int mt = 0; mt < 7; ++mt) {
        bf16x8 qf = *reinterpret_cast<const bf16x8*>(qb + (mt * 16 + l16) * HD + quad * 8);
        f32x4 sacc[7];
#pragma unroll
        for (int nj = 0; nj < 7; ++nj) {
            f32x4 z = {0.f, 0.f, 0.f, 0.f};
            sacc[nj] = __builtin_amdgcn_mfma_f32_16x16x32_bf16(qf, kf[nj], z, 0, 0, 0);
        }
#pragma unroll
        for (int reg = 0; reg < 4; ++reg) {
            int i = mt * 16 + quad * 4 + reg;
            bool irow = (i < NTOK);
            float s[7];
#pragma unroll
            for (int nj = 0; nj < 7; ++nj) {
                int j = nj * 16 + l16;
                float val = -1e30f;
                if (irow && j < NTOK)
                    val = sacc[nj][reg] + bf2f(mbp[i * NTOK + j]);
                s[nj] = val;
            }
            float mx = s[0];
#pragma unroll
            for (int nj = 1; nj < 7; ++nj) mx = fmaxf(mx, s[nj]);
#pragma unroll
            for (int off = 1; off < 16; off <<= 1) mx = fmaxf(mx, __shfl_xor(mx, off));
            float p[7];
            float lsum = 0.f;
#pragma unroll
            for (int nj = 0; nj < 7; ++nj) {
                float pv = (s[nj] > -1e29f) ? __expf(s[nj] - mx) : 0.f;
                p[nj] = pv;
                lsum += pv;
            }
#pragma unroll
            for (int off = 1; off < 16; off <<= 1) lsum += __shfl_xor(lsum, off);
            float rinv = 1.f / ((lsum > 0.f) ? lsum : 1.f);
#pragma unroll
            for (int nj = 0; nj < 7; ++nj) {
                int j = nj * 16 + l16;
                if (irow && j < NTOK)
                    ps[(quad * 4 + reg) * 104 + j] = f2bf(p[nj] * rinv);
            }
        }
        // P (C-layout) -> A-frags via wave-private scratch (no barrier needed)
        bf16x8 pf[3];
#pragma unroll
        for (int ks = 0; ks < 3; ++ks)
            pf[ks] = *reinterpret_cast<const bf16x8*>(&ps[l16 * 104 + quad * 8 + ks * 32]);
#pragma unroll
        for (int nt = 0; nt < 2; ++nt) {
            f32x4 oacc = {0.f, 0.f, 0.f, 0.f};
#pragma unroll
            for (int ks = 0; ks < 3; ++ks) {
                bf16x8 vf = *reinterpret_cast<const bf16x8*>(
                    vb + (nt * 16 + l16) * 104 + quad * 8 + ks * 32);
                oacc = __builtin_amdgcn_mfma_f32_16x16x32_bf16(pf[ks], vf, oacc, 0, 0, 0);
            }
            int d = nt * 16 + l16;
            float v96 = bf2f(vb[d * 104 + 96]);
            float v97 = bf2f(vb[d * 104 + 97]);
#pragma unroll
            for (int reg = 0; reg < 4; ++reg) {
                int i = mt * 16 + quad * 4 + reg;
                if (i < NTOK) {
                    float p96 = bf2f(ps[(quad * 4 + reg) * 104 + 96]);
                    float p97 = bf2f(ps[(quad * 4 + reg) * 104 + 97]);
                    Obuf[i * 136 + h * HD + d] = f2bf(oacc[reg] + p96 * v96 + p97 * v97);
                }
            }
        }
    }

    __syncthreads();

    // proj: out[b] = Obuf @ proj_w^T + proj_b   (7 mt x 8 nt tiles / 4 waves)
    for (int t = wave; t < 56; t += 4) {
        int mt = t >> 3;
        int nt = t & 7;
        int arow = mt * 16 + l16;
        if (arow > 97) arow = 97;
        bf16x8 af[4];
#pragma unroll
        for (int ks = 0; ks < 4; ++ks)
            af[ks] = *reinterpret_cast<const bf16x8*>(&Obuf[arow * 136 + quad * 8 + ks * 32]);
        f32x4 acc = {0.f, 0.f, 0.f, 0.f};
#pragma unroll
        for (int ks = 0; ks < 4; ++ks) {
            bf16x8 bw = *reinterpret_cast<const bf16x8*>(
                pw_bf + (nt * 16 + l16) * DIM + quad * 8 + ks * 32);
            acc = __builtin_amdgcn_mfma_f32_16x16x32_bf16(af[ks], bw, acc, 0, 0, 0);
        }
        int col = nt * 16 + l16;
        float pb = proj_b[col];
#pragma unroll
        for (int reg = 0; reg < 4; ++reg) {
            int row = mt * 16 + quad * 4 + reg;
            if (row < NTOK)
                out[((size_t)b * NTOK + row) * DIM + col] = acc[reg] + pb;
        }
    }
}

// ---------------- launch ------------------------------------------------------
extern "C" void kernel_launch(void* const* d_in, const int* in_sizes, int n_in,
                              void* d_out, int out_size, void* d_ws, size_t ws_size,
                              hipStream_t stream)
{
    const float* x       = (const float*)d_in[0];
    const float* mask    = (const float*)d_in[1];
    const float* qkv_w   = (const float*)d_in[2];
    const float* qkv_b   = (const float*)d_in[3];
    const float* proj_w  = (const float*)d_in[4];
    const float* proj_b  = (const float*)d_in[5];
    const float* bias_tb = (const float*)d_in[6];
    const int*   rel_idx = (const int*)d_in[7];
    float* out = (float*)d_out;

    char* ws = (char*)d_ws;
    u16* qkvw_bf = (u16*)(ws + 0);          //    98304 B
    u16* pw_bf   = (u16*)(ws + 98304);      //    32768 B
    u16* mb      = (u16*)(ws + 131072);     //  4917248 B (64*4*9604 u16)
    u16* qG      = (u16*)(ws + 5048320);    // 51380224 B + pad -> 51381248
    u16* kG      = (u16*)(ws + 56429568);   // 51381248 B
    u16* vG      = (u16*)(ws + 107810816);  // 54525952 B  (2048*4*32*104 u16)
    // total ~162.3 MB

    k0_prep<<<9861, 256, 0, stream>>>(qkv_w, proj_w, mask, bias_tb, rel_idx,
                                      qkvw_bf, pw_bf, mb);
    k1_qkv<<<BWIN, 256, 0, stream>>>(x, qkvw_bf, qkv_b, qG, kG, vG);
    k2_attn<<<BWIN, 256, 0, stream>>>(qG, kG, vG, mb, pw_bf, proj_b, out);
}